// Round 1
// baseline (4781.509 us; speedup 1.0000x reference)
//
#include <hip/hip_runtime.h>
#include <cfloat>
#include <math.h>

// Problem constants
#define NB 2
#define SS 2048
#define HIDN 2048
#define NHH 16
#define DH 128
#define SBI 204       // int(0.1*S)
#define KEEPEND 1844  // S - int(0.1*S)
#define NREC 128      // MERGE_BUDGET
#define NTOPK 16

__device__ __forceinline__ float wave16_max(float x){
  x = fmaxf(x, __shfl_xor(x, 1));
  x = fmaxf(x, __shfl_xor(x, 2));
  x = fmaxf(x, __shfl_xor(x, 4));
  x = fmaxf(x, __shfl_xor(x, 8));
  return x;
}
__device__ __forceinline__ float wave16_sum(float x){
  x += __shfl_xor(x, 1);
  x += __shfl_xor(x, 2);
  x += __shfl_xor(x, 4);
  x += __shfl_xor(x, 8);
  return x;
}

__constant__ const float SCALE_QK = 0.08838834764831845f; // 1/sqrt(128)

__global__ void k_zero(float* __restrict__ p, int n){
  int i = blockIdx.x * 256 + threadIdx.x;
  if (i < n) p[i] = 0.f;
}

// ---------------- QKV GEMM: C[r,c] = sum_k A[r,k]*W[c,k] + bias[c], scatter to q/k/v ----
// A: (4096 x 2048) hidden_states, W: (6144 x 2048) W_qkv (both reduced along contiguous dim)
__global__ __launch_bounds__(256) void k_qkv(
    const float* __restrict__ A, const float* __restrict__ W,
    const float* __restrict__ bias,
    float* __restrict__ q, float* __restrict__ k, float* __restrict__ v)
{
  __shared__ float As[64][33];
  __shared__ float Bs[64][33];
  const int tid = threadIdx.x;
  const int tx = tid & 15, ty = tid >> 4;
  const int row0 = blockIdx.y * 64;
  const int col0 = blockIdx.x * 64;

  float acc[4][4] = {};
  for (int k0 = 0; k0 < HIDN; k0 += 32){
    __syncthreads();
    #pragma unroll
    for (int it = 0; it < 2; ++it){
      int idx = tid + it * 256;
      int row = idx >> 3, fq = (idx & 7) * 4;
      float4 a4 = *(const float4*)(A + (size_t)(row0 + row) * HIDN + k0 + fq);
      float4 b4 = *(const float4*)(W + (size_t)(col0 + row) * HIDN + k0 + fq);
      As[row][fq+0] = a4.x; As[row][fq+1] = a4.y; As[row][fq+2] = a4.z; As[row][fq+3] = a4.w;
      Bs[row][fq+0] = b4.x; Bs[row][fq+1] = b4.y; Bs[row][fq+2] = b4.z; Bs[row][fq+3] = b4.w;
    }
    __syncthreads();
    #pragma unroll
    for (int kk = 0; kk < 32; ++kk){
      float a[4], b[4];
      #pragma unroll
      for (int i = 0; i < 4; ++i) a[i] = As[ty + 16*i][kk];
      #pragma unroll
      for (int j = 0; j < 4; ++j) b[j] = Bs[tx + 16*j][kk];
      #pragma unroll
      for (int i = 0; i < 4; ++i)
        #pragma unroll
        for (int j = 0; j < 4; ++j)
          acc[i][j] += a[i] * b[j];
    }
  }
  #pragma unroll
  for (int i = 0; i < 4; ++i){
    const int r  = row0 + ty + 16*i;
    const int b_ = r >> 11;          // r / S
    const int s_ = r & (SS - 1);
    #pragma unroll
    for (int j = 0; j < 4; ++j){
      const int c = col0 + tx + 16*j;
      const float val = acc[i][j] + bias[c];
      const int h_ = c / 384;
      const int w  = c - h_ * 384;
      float* dst; int d;
      if (w < DH)        { dst = q; d = w; }
      else if (w < 2*DH) { dst = k; d = w - DH; }
      else               { dst = v; d = w - 2*DH; }
      dst[(size_t)((b_*NHH + h_)*SS + s_)*DH + d] = val;
    }
  }
}

// ---------------- RoPE in-place on q and k (first 32 dims, pair (d, d+16)) ----------------
__global__ void k_rope(float* __restrict__ q, float* __restrict__ k,
                       const int* __restrict__ pos_ids)
{
  const int idx = blockIdx.x * 256 + threadIdx.x;  // 2*B*H*S*16 threads
  const int d = idx & 15;
  int t = idx >> 4;
  const int s  = t & (SS - 1); t >>= 11;
  const int h_ = t & 15;       t >>= 4;
  const int b_ = t & 1;
  const int which = t >> 1;
  float* base = (which ? k : q) + (size_t)((b_*NHH + h_)*SS + s) * DH;
  const float p = (float)pos_ids[b_*SS + s];
  const float invf = expf(-(float)d * 0.5756462732485115f); // ln(10000)/16
  float sn, cs;
  sincosf(p * invf, &sn, &cs);
  const float x0 = base[d], x1 = base[d + 16];
  base[d]      = x0 * cs - x1 * sn;
  base[d + 16] = x1 * cs + x0 * sn;
}

// ---------------- Pass A: per-row softmax max m and denom l (online) ----------------------
// grid: B*H*(S/32), block 256 (=16x16), q-tile 32, k-tile 64
__global__ __launch_bounds__(256) void k_passA(
    const float* __restrict__ qg_, const float* __restrict__ kg_,
    const float* __restrict__ amask,
    float* __restrict__ mrow, float* __restrict__ lrow)
{
  __shared__ float Qs[32][129];
  __shared__ float Ks[64][129];
  const int tid = threadIdx.x;
  const int tx = tid & 15, ty = tid >> 4, ty2 = ty * 2;
  const int qb = blockIdx.x & 63;
  const int bh = blockIdx.x >> 6;
  const int b_ = bh >> 4;
  const int q0 = qb * 32;
  const float* qbase = qg_ + (size_t)bh * SS * DH;
  const float* kbase = kg_ + (size_t)bh * SS * DH;
  const float* mk = amask + b_ * SS;

  #pragma unroll
  for (int it = 0; it < 4; ++it){
    int idx = tid + it * 256;
    int row = idx >> 5, fq = (idx & 31) * 4;
    float4 t4 = *(const float4*)(qbase + (size_t)(q0 + row) * DH + fq);
    Qs[row][fq+0] = t4.x; Qs[row][fq+1] = t4.y; Qs[row][fq+2] = t4.z; Qs[row][fq+3] = t4.w;
  }

  float m_run[2] = { -FLT_MAX, -FLT_MAX };
  float l_run[2] = { 0.f, 0.f };
  const int n_kt = (q0 + 31) / 64 + 1;

  for (int kt = 0; kt < n_kt; ++kt){
    const int kt64 = kt * 64;
    __syncthreads();
    #pragma unroll
    for (int it = 0; it < 8; ++it){
      int idx = tid + it * 256;
      int row = idx >> 5, fq = (idx & 31) * 4;
      float4 t4 = *(const float4*)(kbase + (size_t)(kt64 + row) * DH + fq);
      Ks[row][fq+0] = t4.x; Ks[row][fq+1] = t4.y; Ks[row][fq+2] = t4.z; Ks[row][fq+3] = t4.w;
    }
    __syncthreads();
    float acc[2][4] = {};
    #pragma unroll 4
    for (int d = 0; d < DH; ++d){
      float a0 = Qs[ty2][d], a1 = Qs[ty2 + 1][d];
      #pragma unroll
      for (int j = 0; j < 4; ++j){
        float bj = Ks[tx + 16*j][d];
        acc[0][j] += a0 * bj;
        acc[1][j] += a1 * bj;
      }
    }
    #pragma unroll
    for (int i = 0; i < 2; ++i){
      const int qg = q0 + ty2 + i;
      float s[4]; float tmax = -FLT_MAX;
      #pragma unroll
      for (int j = 0; j < 4; ++j){
        const int kk2 = kt64 + tx + 16*j;
        float sv = (kk2 <= qg) ? acc[i][j] * SCALE_QK + mk[kk2] : -FLT_MAX;
        s[j] = sv;
        tmax = fmaxf(tmax, sv);
      }
      tmax = wave16_max(tmax);
      float ts = 0.f;
      #pragma unroll
      for (int j = 0; j < 4; ++j) ts += __expf(s[j] - tmax);
      ts = wave16_sum(ts);
      if (tmax > -1e37f){
        float mn = fmaxf(m_run[i], tmax);
        l_run[i] = l_run[i] * __expf(m_run[i] - mn) + ts * __expf(tmax - mn);
        m_run[i] = mn;
      }
    }
  }
  if (tx == 0){
    #pragma unroll
    for (int i = 0; i < 2; ++i){
      mrow[(size_t)bh * SS + q0 + ty2 + i] = m_run[i];
      lrow[(size_t)bh * SS + q0 + ty2 + i] = l_run[i];
    }
  }
}

// ---------------- Pass B: exact probs, P@V accumulate, column sums ------------------------
__global__ __launch_bounds__(256) void k_passB(
    const float* __restrict__ qg_, const float* __restrict__ kg_, const float* __restrict__ vg_,
    const float* __restrict__ amask,
    const float* __restrict__ mrow, const float* __restrict__ lrow,
    float* __restrict__ attn_out,
    float* __restrict__ colsum_all, float* __restrict__ colsum_recent)
{
  __shared__ float Qs[32][129];
  __shared__ float KVs[64][129];   // K tile, then reused for V tile
  __shared__ float Ps[32][65];
  const int tid = threadIdx.x;
  const int tx = tid & 15, ty = tid >> 4, ty2 = ty * 2;
  const int qb = blockIdx.x & 63;
  const int bh = blockIdx.x >> 6;
  const int h_ = bh & 15, b_ = bh >> 4;
  const int q0 = qb * 32;
  const float* qbase = qg_ + (size_t)bh * SS * DH;
  const float* kbase = kg_ + (size_t)bh * SS * DH;
  const float* vbase = vg_ + (size_t)bh * SS * DH;
  const float* mk = amask + b_ * SS;

  #pragma unroll
  for (int it = 0; it < 4; ++it){
    int idx = tid + it * 256;
    int row = idx >> 5, fq = (idx & 31) * 4;
    float4 t4 = *(const float4*)(qbase + (size_t)(q0 + row) * DH + fq);
    Qs[row][fq+0] = t4.x; Qs[row][fq+1] = t4.y; Qs[row][fq+2] = t4.z; Qs[row][fq+3] = t4.w;
  }
  float mi[2], rl[2];
  #pragma unroll
  for (int i = 0; i < 2; ++i){
    mi[i] = mrow[(size_t)bh * SS + q0 + ty2 + i];
    rl[i] = 1.f / lrow[(size_t)bh * SS + q0 + ty2 + i];
  }

  float o[2][8] = {};
  const int n_kt = (q0 + 31) / 64 + 1;
  const bool recent = (q0 >= SS - NREC);

  for (int kt = 0; kt < n_kt; ++kt){
    const int kt64 = kt * 64;
    __syncthreads();   // prev PV done: safe to overwrite KVs / Ps
    #pragma unroll
    for (int it = 0; it < 8; ++it){
      int idx = tid + it * 256;
      int row = idx >> 5, fq = (idx & 31) * 4;
      float4 t4 = *(const float4*)(kbase + (size_t)(kt64 + row) * DH + fq);
      KVs[row][fq+0] = t4.x; KVs[row][fq+1] = t4.y; KVs[row][fq+2] = t4.z; KVs[row][fq+3] = t4.w;
    }
    __syncthreads();
    float acc[2][4] = {};
    #pragma unroll 4
    for (int d = 0; d < DH; ++d){
      float a0 = Qs[ty2][d], a1 = Qs[ty2 + 1][d];
      #pragma unroll
      for (int j = 0; j < 4; ++j){
        float bj = KVs[tx + 16*j][d];
        acc[0][j] += a0 * bj;
        acc[1][j] += a1 * bj;
      }
    }
    #pragma unroll
    for (int i = 0; i < 2; ++i){
      const int qg = q0 + ty2 + i;
      #pragma unroll
      for (int j = 0; j < 4; ++j){
        const int kk2 = kt64 + tx + 16*j;
        float p = 0.f;
        if (kk2 <= qg) p = __expf(acc[i][j] * SCALE_QK + mk[kk2] - mi[i]) * rl[i];
        Ps[ty2 + i][tx + 16*j] = p;
      }
    }
    __syncthreads();   // Ps ready; K tile fully consumed
    #pragma unroll
    for (int it = 0; it < 8; ++it){
      int idx = tid + it * 256;
      int row = idx >> 5, fq = (idx & 31) * 4;
      float4 t4 = *(const float4*)(vbase + (size_t)(kt64 + row) * DH + fq);
      KVs[row][fq+0] = t4.x; KVs[row][fq+1] = t4.y; KVs[row][fq+2] = t4.z; KVs[row][fq+3] = t4.w;
    }
    if (tid < 64){
      float cs = 0.f;
      #pragma unroll
      for (int r = 0; r < 32; ++r) cs += Ps[r][tid];
      atomicAdd(colsum_all + h_ * SS + kt64 + tid, cs);
      if (recent) atomicAdd(colsum_recent + h_ * SS + kt64 + tid, cs);
    }
    __syncthreads();   // V tile + Ps ready for PV
    #pragma unroll 2
    for (int kk = 0; kk < 64; ++kk){
      float p0 = Ps[ty2][kk], p1 = Ps[ty2 + 1][kk];
      #pragma unroll
      for (int j = 0; j < 8; ++j){
        float vv = KVs[kk][tx + 16*j];
        o[0][j] += p0 * vv;
        o[1][j] += p1 * vv;
      }
    }
  }
  #pragma unroll
  for (int i = 0; i < 2; ++i){
    float* orow = attn_out + (size_t)(b_*SS + q0 + ty2 + i) * HIDN + h_ * DH;
    #pragma unroll
    for (int j = 0; j < 8; ++j) orow[tx + 16*j] = o[i][j];
  }
}

// ---------------- attention column at k = sb (from stored m,l) ----------------------------
__global__ __launch_bounds__(256) void k_colsb(
    const float* __restrict__ qg_, const float* __restrict__ kg_,
    const float* __restrict__ amask,
    const float* __restrict__ mrow, const float* __restrict__ lrow,
    float* __restrict__ acol)
{
  __shared__ __align__(16) float ksb[DH];
  const int tid = threadIdx.x;
  const int qc = blockIdx.x & 31;
  const int bh = blockIdx.x >> 5;
  const int b_ = bh >> 4;
  if (tid < 32)
    ((float4*)ksb)[tid] = ((const float4*)(kg_ + (size_t)(bh * SS + SBI) * DH))[tid];
  __syncthreads();
  const int ql = tid >> 2, part = tid & 3;
  const int qg = qc * 64 + ql;
  const float* qrow = qg_ + (size_t)(bh * SS + qg) * DH + part * 32;
  float acc = 0.f;
  #pragma unroll
  for (int t = 0; t < 8; ++t){
    float4 a4 = ((const float4*)qrow)[t];
    float4 k4 = ((const float4*)(ksb + part * 32))[t];
    acc += a4.x*k4.x + a4.y*k4.y + a4.z*k4.z + a4.w*k4.w;
  }
  acc += __shfl_xor(acc, 1);
  acc += __shfl_xor(acc, 2);
  if (part == 0){
    float a = 0.f;
    if (qg >= SBI){
      float m = mrow[(size_t)bh * SS + qg];
      float l = lrow[(size_t)bh * SS + qg];
      a = __expf(acc * SCALE_QK + amask[b_*SS + SBI] - m) / l;
    }
    acol[(size_t)bh * SS + qg] = a;
  }
}

// ---------------- topk per head + score1 ---------------------------------------------------
__global__ __launch_bounds__(256) void k_topk(
    const float* __restrict__ colsum_all, const float* __restrict__ colsum_recent,
    const float* __restrict__ vg_, float* __restrict__ score1)
{
  __shared__ float vals[KEEPEND];
  __shared__ float rv[256];
  __shared__ int   ri[256];
  __shared__ int   sidx[NTOPK];
  __shared__ float sratio[NTOPK];
  const int h_ = blockIdx.x;
  const int tid = threadIdx.x;
  for (int i = SBI + tid; i < KEEPEND; i += 256) vals[i] = colsum_all[h_*SS + i];
  __syncthreads();
  for (int it = 0; it < NTOPK; ++it){
    float bv = -1.f; int bi = 0x7fffffff;
    for (int i = SBI + tid; i < KEEPEND; i += 256){
      float x = vals[i];
      if (x > bv){ bv = x; bi = i; }   // ascending scan keeps lowest index on ties
    }
    rv[tid] = bv; ri[tid] = bi;
    __syncthreads();
    for (int s2 = 128; s2 > 0; s2 >>= 1){
      if (tid < s2){
        float ov = rv[tid + s2]; int oi = ri[tid + s2];
        if (ov > rv[tid] || (ov == rv[tid] && oi < ri[tid])){ rv[tid] = ov; ri[tid] = oi; }
      }
      __syncthreads();
    }
    if (tid == 0){ sidx[it] = ri[0]; vals[ri[0]] = -1.f; }
    __syncthreads();
  }
  if (tid < NTOPK) sratio[tid] = colsum_recent[h_*SS + sidx[tid]] * (1.f / NREC);
  __syncthreads();
  const int b_ = tid >> 7, d = tid & 127;
  float acc = 0.f;
  #pragma unroll
  for (int j = 0; j < NTOPK; ++j)
    acc += sratio[j] * vg_[(size_t)((b_*NHH + h_)*SS + sidx[j])*DH + d];
  score1[(b_*NHH + h_)*DH + d] = acc;
}

// ---------------- rank-1 correction: out += attn[:,sb] * (score1 - v[sb]) ----------------
__global__ void k_corr(const float* __restrict__ acol, const float* __restrict__ score1,
                       const float* __restrict__ vg_, float* __restrict__ attn_out)
{
  const int idx = blockIdx.x * 256 + threadIdx.x;  // B*H*S*32 threads (float4 over d)
  const int dq = idx & 31;
  int t = idx >> 5;
  const int qg = t & (SS - 1); t >>= 11;
  const int h_ = t & 15;
  const int b_ = t >> 4;
  const float a = acol[(size_t)(b_*NHH + h_) * SS + qg];
  if (a != 0.f){
    const int d = dq * 4;
    const float4 s1 = *(const float4*)(score1 + (b_*NHH + h_) * DH + d);
    const float4 vs = *(const float4*)(vg_ + (size_t)((b_*NHH + h_)*SS + SBI) * DH + d);
    float4* op = (float4*)(attn_out + (size_t)(b_*SS + qg) * HIDN + h_ * DH + d);
    float4 ov = *op;
    ov.x += a * (s1.x - vs.x);
    ov.y += a * (s1.y - vs.y);
    ov.z += a * (s1.z - vs.z);
    ov.w += a * (s1.w - vs.w);
    *op = ov;
  }
}

// ---------------- dense GEMM: out[r,c] = sum_k A[r,k]*W[c,k] + bias[c] --------------------
__global__ __launch_bounds__(256) void k_dense(
    const float* __restrict__ A, const float* __restrict__ W,
    const float* __restrict__ bias, float* __restrict__ out)
{
  __shared__ float As[64][33];
  __shared__ float Bs[64][33];
  const int tid = threadIdx.x;
  const int tx = tid & 15, ty = tid >> 4;
  const int row0 = blockIdx.y * 64;
  const int col0 = blockIdx.x * 64;

  float acc[4][4] = {};
  for (int k0 = 0; k0 < HIDN; k0 += 32){
    __syncthreads();
    #pragma unroll
    for (int it = 0; it < 2; ++it){
      int idx = tid + it * 256;
      int row = idx >> 3, fq = (idx & 7) * 4;
      float4 a4 = *(const float4*)(A + (size_t)(row0 + row) * HIDN + k0 + fq);
      float4 b4 = *(const float4*)(W + (size_t)(col0 + row) * HIDN + k0 + fq);
      As[row][fq+0] = a4.x; As[row][fq+1] = a4.y; As[row][fq+2] = a4.z; As[row][fq+3] = a4.w;
      Bs[row][fq+0] = b4.x; Bs[row][fq+1] = b4.y; Bs[row][fq+2] = b4.z; Bs[row][fq+3] = b4.w;
    }
    __syncthreads();
    #pragma unroll
    for (int kk = 0; kk < 32; ++kk){
      float a[4], b[4];
      #pragma unroll
      for (int i = 0; i < 4; ++i) a[i] = As[ty + 16*i][kk];
      #pragma unroll
      for (int j = 0; j < 4; ++j) b[j] = Bs[tx + 16*j][kk];
      #pragma unroll
      for (int i = 0; i < 4; ++i)
        #pragma unroll
        for (int j = 0; j < 4; ++j)
          acc[i][j] += a[i] * b[j];
    }
  }
  #pragma unroll
  for (int i = 0; i < 4; ++i){
    const int r = row0 + ty + 16*i;
    #pragma unroll
    for (int j = 0; j < 4; ++j){
      const int c = col0 + tx + 16*j;
      out[(size_t)r * HIDN + c] = acc[i][j] + bias[c];
    }
  }
}

extern "C" void kernel_launch(void* const* d_in, const int* in_sizes, int n_in,
                              void* d_out, int out_size, void* d_ws, size_t ws_size,
                              hipStream_t stream)
{
  (void)in_sizes; (void)n_in; (void)out_size; (void)ws_size;
  const float* hs    = (const float*)d_in[0];
  const float* amask = (const float*)d_in[1];
  const int*   pos   = (const int*)d_in[2];
  const float* Wqkv  = (const float*)d_in[3];
  const float* bqkv  = (const float*)d_in[4];
  const float* Wd    = (const float*)d_in[5];
  const float* bd    = (const float*)d_in[6];
  float* out = (float*)d_out;
  float* ws  = (float*)d_ws;

  const size_t SZ = (size_t)NB * NHH * SS * DH;   // 8,388,608 floats per tensor
  float* q             = ws;
  float* k             = q + SZ;
  float* v             = k + SZ;
  float* mrow          = v + SZ;                        // B*H*S
  float* lrow          = mrow + (size_t)NB*NHH*SS;
  float* colsum_all    = lrow + (size_t)NB*NHH*SS;      // H*S
  float* colsum_recent = colsum_all + (size_t)NHH*SS;   // H*S
  float* acol          = colsum_recent + (size_t)NHH*SS;// B*H*S
  float* score1        = acol + (size_t)NB*NHH*SS;      // B*H*D
  float* attn_out      = score1 + (size_t)NB*NHH*DH;    // B*S*HID

  k_zero<<<256, 256, 0, stream>>>(colsum_all, NHH * SS * 2);
  k_qkv<<<dim3(96, 64), 256, 0, stream>>>(hs, Wqkv, bqkv, q, k, v);
  k_rope<<<8192, 256, 0, stream>>>(q, k, pos);
  k_passA<<<NB*NHH*(SS/32), 256, 0, stream>>>(q, k, amask, mrow, lrow);
  k_passB<<<NB*NHH*(SS/32), 256, 0, stream>>>(q, k, v, amask, mrow, lrow,
                                              attn_out, colsum_all, colsum_recent);
  k_colsb<<<NB*NHH*(SS/64), 256, 0, stream>>>(q, k, amask, mrow, lrow, acol);
  k_topk<<<NHH, 256, 0, stream>>>(colsum_all, colsum_recent, v, score1);
  k_corr<<<(NB*NHH*SS*32)/256, 256, 0, stream>>>(acol, score1, v, attn_out);
  k_dense<<<dim3(32, 64), 256, 0, stream>>>(attn_out, Wd, bd, out);
}

// Round 2
// 2587.007 us; speedup vs baseline: 1.8483x; 1.8483x over previous
//
#include <hip/hip_runtime.h>
#include <cfloat>
#include <math.h>

// Problem constants
#define NB 2
#define SS 2048
#define HIDN 2048
#define NHH 16
#define DH 128
#define SBI 204       // int(0.1*S)
#define KEEPEND 1844  // S - int(0.1*S)
#define NREC 128      // MERGE_BUDGET
#define NTOPK 16

typedef short bf16x8 __attribute__((ext_vector_type(8)));
typedef float f32x4  __attribute__((ext_vector_type(4)));
typedef unsigned short ushort8_v __attribute__((ext_vector_type(8)));

#define GLOBAL_AS __attribute__((address_space(1)))
#define LDS_AS    __attribute__((address_space(3)))

__device__ __forceinline__ void async16(const ushort* g, ushort* l){
  __builtin_amdgcn_global_load_lds((const GLOBAL_AS void*)g, (LDS_AS void*)l, 16, 0, 0);
}

__device__ __forceinline__ unsigned short f2bf(float x){
  union { float f; unsigned u; } cv; cv.f = x;
  unsigned u = cv.u;
  return (unsigned short)((u + 0x7fffu + ((u >> 16) & 1u)) >> 16);
}

__device__ __forceinline__ float wave16_max(float x){
  x = fmaxf(x, __shfl_xor(x, 1));
  x = fmaxf(x, __shfl_xor(x, 2));
  x = fmaxf(x, __shfl_xor(x, 4));
  x = fmaxf(x, __shfl_xor(x, 8));
  return x;
}
__device__ __forceinline__ float wave16_sum(float x){
  x += __shfl_xor(x, 1);
  x += __shfl_xor(x, 2);
  x += __shfl_xor(x, 4);
  x += __shfl_xor(x, 8);
  return x;
}

__constant__ const float SCALE_QK = 0.08838834764831845f; // 1/sqrt(128)

__global__ void k_zero(float* __restrict__ p, int n){
  int i = blockIdx.x * 256 + threadIdx.x;
  if (i < n) p[i] = 0.f;
}

// ---------------- fp32 -> bf16 convert (8 elems/thread) -----------------------------------
__global__ void k_f2bf(const float* __restrict__ src, unsigned short* __restrict__ dst, int n8){
  int i = blockIdx.x * 256 + threadIdx.x;
  if (i >= n8) return;
  const float4* s = (const float4*)src + (size_t)i * 2;
  float4 a = s[0], b = s[1];
  ushort8_v r;
  r[0] = f2bf(a.x); r[1] = f2bf(a.y); r[2] = f2bf(a.z); r[3] = f2bf(a.w);
  r[4] = f2bf(b.x); r[5] = f2bf(b.y); r[6] = f2bf(b.z); r[7] = f2bf(b.w);
  *(ushort8_v*)(dst + (size_t)i * 8) = r;
}

// ---------------- bf16 MFMA GEMM (m97 structure): C = A @ W^T -----------------------------
// A: M x 2048 bf16 row-major, W: N x 2048 bf16 row-major. 128x128 tile, BK=32.
// QKV variant: scatters into q/k/v with fused RoPE on first 32 dims of q,k.
__global__ __launch_bounds__(256) void k_gemm_qkv(
    const unsigned short* __restrict__ A, const unsigned short* __restrict__ W,
    const float* __restrict__ bias, const int* __restrict__ pos,
    float* __restrict__ q, float* __restrict__ k, float* __restrict__ v)
{
  __shared__ __align__(16) unsigned short As[128 * 32];
  __shared__ __align__(16) unsigned short Bs[128 * 32];
  const int tid  = threadIdx.x;
  const int lane = tid & 63, w = tid >> 6;
  const int wm = w >> 1, wn = w & 1;
  const int quad = lane >> 4, m16 = lane & 15;
  const int cb   = blockIdx.x;          // col block (N/128)
  const int row0 = blockIdx.y * 128;
  const int col0 = cb * 128;

  const int srow = tid >> 2;            // 0..63
  const int scol = (tid & 3) * 8;       // bf16 element col
  const unsigned short* ga = A + (size_t)(row0 + srow) * HIDN + scol;
  const unsigned short* gb = W + (size_t)(col0 + srow) * HIDN + scol;
  unsigned short* la = As + tid * 8;
  unsigned short* lb = Bs + tid * 8;

  f32x4 acc[4][4];
  #pragma unroll
  for (int i = 0; i < 4; ++i)
    #pragma unroll
    for (int j = 0; j < 4; ++j)
      acc[i][j] = (f32x4){0.f, 0.f, 0.f, 0.f};

  for (int k0 = 0; k0 < HIDN; k0 += 32){
    __syncthreads();
    async16(ga + k0,             la);
    async16(ga + k0 + 64 * HIDN, la + 64 * 32);
    async16(gb + k0,             lb);
    async16(gb + k0 + 64 * HIDN, lb + 64 * 32);
    __syncthreads();
    bf16x8 af[4], bf[4];
    #pragma unroll
    for (int j = 0; j < 4; ++j)
      bf[j] = *(const bf16x8*)(Bs + (wn * 64 + j * 16 + m16) * 32 + quad * 8);
    #pragma unroll
    for (int i = 0; i < 4; ++i)
      af[i] = *(const bf16x8*)(As + (wm * 64 + i * 16 + m16) * 32 + quad * 8);
    #pragma unroll
    for (int i = 0; i < 4; ++i)
      #pragma unroll
      for (int j = 0; j < 4; ++j)
        acc[i][j] = __builtin_amdgcn_mfma_f32_16x16x32_bf16(af[i], bf[j], acc[i][j], 0, 0, 0);
  }

  // Epilogue: col block cb covers exactly one of q/k/v for head h (384 = 3*128)
  const int h  = cb / 3, r3 = cb - 3 * (cb / 3);
  float* dst = (r3 == 0) ? q : ((r3 == 1) ? k : v);
  const bool do_rope = (r3 < 2) && (wn == 0);
  const float invf = __expf(-(float)m16 * 0.5756462732485115f); // ln(10000)/16

  #pragma unroll
  for (int i = 0; i < 4; ++i){
    #pragma unroll
    for (int reg = 0; reg < 4; ++reg){
      const int mr = row0 + wm * 64 + i * 16 + quad * 4 + reg;
      const int b_ = mr >> 11, s_ = mr & (SS - 1);
      float* drow = dst + (size_t)((b_ * NHH + h) * SS + s_) * DH;
      float vals[4];
      #pragma unroll
      for (int j = 0; j < 4; ++j)
        vals[j] = acc[i][j][reg] + bias[col0 + wn * 64 + j * 16 + m16];
      if (do_rope){
        float sn, cs;
        const float p = (float)pos[b_ * SS + s_];
        sincosf(p * invf, &sn, &cs);
        const float x0 = vals[0], x1 = vals[1];
        vals[0] = x0 * cs - x1 * sn;
        vals[1] = x1 * cs + x0 * sn;
      }
      #pragma unroll
      for (int j = 0; j < 4; ++j)
        drow[wn * 64 + j * 16 + m16] = vals[j];
    }
  }
}

// Dense variant: plain C = A @ W^T + bias
__global__ __launch_bounds__(256) void k_gemm_dense(
    const unsigned short* __restrict__ A, const unsigned short* __restrict__ W,
    const float* __restrict__ bias, float* __restrict__ out)
{
  __shared__ __align__(16) unsigned short As[128 * 32];
  __shared__ __align__(16) unsigned short Bs[128 * 32];
  const int tid  = threadIdx.x;
  const int lane = tid & 63, w = tid >> 6;
  const int wm = w >> 1, wn = w & 1;
  const int quad = lane >> 4, m16 = lane & 15;
  const int row0 = blockIdx.y * 128;
  const int col0 = blockIdx.x * 128;

  const int srow = tid >> 2;
  const int scol = (tid & 3) * 8;
  const unsigned short* ga = A + (size_t)(row0 + srow) * HIDN + scol;
  const unsigned short* gb = W + (size_t)(col0 + srow) * HIDN + scol;
  unsigned short* la = As + tid * 8;
  unsigned short* lb = Bs + tid * 8;

  f32x4 acc[4][4];
  #pragma unroll
  for (int i = 0; i < 4; ++i)
    #pragma unroll
    for (int j = 0; j < 4; ++j)
      acc[i][j] = (f32x4){0.f, 0.f, 0.f, 0.f};

  for (int k0 = 0; k0 < HIDN; k0 += 32){
    __syncthreads();
    async16(ga + k0,             la);
    async16(ga + k0 + 64 * HIDN, la + 64 * 32);
    async16(gb + k0,             lb);
    async16(gb + k0 + 64 * HIDN, lb + 64 * 32);
    __syncthreads();
    bf16x8 af[4], bf[4];
    #pragma unroll
    for (int j = 0; j < 4; ++j)
      bf[j] = *(const bf16x8*)(Bs + (wn * 64 + j * 16 + m16) * 32 + quad * 8);
    #pragma unroll
    for (int i = 0; i < 4; ++i)
      af[i] = *(const bf16x8*)(As + (wm * 64 + i * 16 + m16) * 32 + quad * 8);
    #pragma unroll
    for (int i = 0; i < 4; ++i)
      #pragma unroll
      for (int j = 0; j < 4; ++j)
        acc[i][j] = __builtin_amdgcn_mfma_f32_16x16x32_bf16(af[i], bf[j], acc[i][j], 0, 0, 0);
  }

  #pragma unroll
  for (int i = 0; i < 4; ++i){
    #pragma unroll
    for (int reg = 0; reg < 4; ++reg){
      const int mr = row0 + wm * 64 + i * 16 + quad * 4 + reg;
      #pragma unroll
      for (int j = 0; j < 4; ++j){
        const int c = col0 + wn * 64 + j * 16 + m16;
        out[(size_t)mr * HIDN + c] = acc[i][j][reg] + bias[c];
      }
    }
  }
}

// ---------------- Pass A: per-row softmax max m and denom l (online) ----------------------
__global__ __launch_bounds__(256) void k_passA(
    const float* __restrict__ qg_, const float* __restrict__ kg_,
    const float* __restrict__ amask,
    float* __restrict__ mrow, float* __restrict__ lrow)
{
  __shared__ float Qs[32][129];
  __shared__ float Ks[64][129];
  const int tid = threadIdx.x;
  const int tx = tid & 15, ty = tid >> 4, ty2 = ty * 2;
  const int qb = blockIdx.x & 63;
  const int bh = blockIdx.x >> 6;
  const int b_ = bh >> 4;
  const int q0 = qb * 32;
  const float* qbase = qg_ + (size_t)bh * SS * DH;
  const float* kbase = kg_ + (size_t)bh * SS * DH;
  const float* mk = amask + b_ * SS;

  #pragma unroll
  for (int it = 0; it < 4; ++it){
    int idx = tid + it * 256;
    int row = idx >> 5, fq = (idx & 31) * 4;
    float4 t4 = *(const float4*)(qbase + (size_t)(q0 + row) * DH + fq);
    Qs[row][fq+0] = t4.x; Qs[row][fq+1] = t4.y; Qs[row][fq+2] = t4.z; Qs[row][fq+3] = t4.w;
  }

  float m_run[2] = { -FLT_MAX, -FLT_MAX };
  float l_run[2] = { 0.f, 0.f };
  const int n_kt = (q0 + 31) / 64 + 1;

  for (int kt = 0; kt < n_kt; ++kt){
    const int kt64 = kt * 64;
    __syncthreads();
    #pragma unroll
    for (int it = 0; it < 8; ++it){
      int idx = tid + it * 256;
      int row = idx >> 5, fq = (idx & 31) * 4;
      float4 t4 = *(const float4*)(kbase + (size_t)(kt64 + row) * DH + fq);
      Ks[row][fq+0] = t4.x; Ks[row][fq+1] = t4.y; Ks[row][fq+2] = t4.z; Ks[row][fq+3] = t4.w;
    }
    __syncthreads();
    float acc[2][4] = {};
    #pragma unroll 4
    for (int d = 0; d < DH; ++d){
      float a0 = Qs[ty2][d], a1 = Qs[ty2 + 1][d];
      #pragma unroll
      for (int j = 0; j < 4; ++j){
        float bj = Ks[tx + 16*j][d];
        acc[0][j] += a0 * bj;
        acc[1][j] += a1 * bj;
      }
    }
    #pragma unroll
    for (int i = 0; i < 2; ++i){
      const int qg = q0 + ty2 + i;
      float s[4]; float tmax = -FLT_MAX;
      #pragma unroll
      for (int j = 0; j < 4; ++j){
        const int kk2 = kt64 + tx + 16*j;
        float sv = (kk2 <= qg) ? acc[i][j] * SCALE_QK + mk[kk2] : -FLT_MAX;
        s[j] = sv;
        tmax = fmaxf(tmax, sv);
      }
      tmax = wave16_max(tmax);
      float ts = 0.f;
      #pragma unroll
      for (int j = 0; j < 4; ++j) ts += __expf(s[j] - tmax);
      ts = wave16_sum(ts);
      if (tmax > -1e37f){
        float mn = fmaxf(m_run[i], tmax);
        l_run[i] = l_run[i] * __expf(m_run[i] - mn) + ts * __expf(tmax - mn);
        m_run[i] = mn;
      }
    }
  }
  if (tx == 0){
    #pragma unroll
    for (int i = 0; i < 2; ++i){
      mrow[(size_t)bh * SS + q0 + ty2 + i] = m_run[i];
      lrow[(size_t)bh * SS + q0 + ty2 + i] = l_run[i];
    }
  }
}

// ---------------- Pass B: exact probs, P@V accumulate, column sums ------------------------
__global__ __launch_bounds__(256) void k_passB(
    const float* __restrict__ qg_, const float* __restrict__ kg_, const float* __restrict__ vg_,
    const float* __restrict__ amask,
    const float* __restrict__ mrow, const float* __restrict__ lrow,
    float* __restrict__ attn_out,
    float* __restrict__ colsum_all, float* __restrict__ colsum_recent)
{
  __shared__ float Qs[32][129];
  __shared__ float KVs[64][129];
  __shared__ float Ps[32][65];
  const int tid = threadIdx.x;
  const int tx = tid & 15, ty = tid >> 4, ty2 = ty * 2;
  const int qb = blockIdx.x & 63;
  const int bh = blockIdx.x >> 6;
  const int h_ = bh & 15, b_ = bh >> 4;
  const int q0 = qb * 32;
  const float* qbase = qg_ + (size_t)bh * SS * DH;
  const float* kbase = kg_ + (size_t)bh * SS * DH;
  const float* vbase = vg_ + (size_t)bh * SS * DH;
  const float* mk = amask + b_ * SS;

  #pragma unroll
  for (int it = 0; it < 4; ++it){
    int idx = tid + it * 256;
    int row = idx >> 5, fq = (idx & 31) * 4;
    float4 t4 = *(const float4*)(qbase + (size_t)(q0 + row) * DH + fq);
    Qs[row][fq+0] = t4.x; Qs[row][fq+1] = t4.y; Qs[row][fq+2] = t4.z; Qs[row][fq+3] = t4.w;
  }
  float mi[2], rl[2];
  #pragma unroll
  for (int i = 0; i < 2; ++i){
    mi[i] = mrow[(size_t)bh * SS + q0 + ty2 + i];
    rl[i] = 1.f / lrow[(size_t)bh * SS + q0 + ty2 + i];
  }

  float o[2][8] = {};
  const int n_kt = (q0 + 31) / 64 + 1;
  const bool recent = (q0 >= SS - NREC);

  for (int kt = 0; kt < n_kt; ++kt){
    const int kt64 = kt * 64;
    __syncthreads();
    #pragma unroll
    for (int it = 0; it < 8; ++it){
      int idx = tid + it * 256;
      int row = idx >> 5, fq = (idx & 31) * 4;
      float4 t4 = *(const float4*)(kbase + (size_t)(kt64 + row) * DH + fq);
      KVs[row][fq+0] = t4.x; KVs[row][fq+1] = t4.y; KVs[row][fq+2] = t4.z; KVs[row][fq+3] = t4.w;
    }
    __syncthreads();
    float acc[2][4] = {};
    #pragma unroll 4
    for (int d = 0; d < DH; ++d){
      float a0 = Qs[ty2][d], a1 = Qs[ty2 + 1][d];
      #pragma unroll
      for (int j = 0; j < 4; ++j){
        float bj = KVs[tx + 16*j][d];
        acc[0][j] += a0 * bj;
        acc[1][j] += a1 * bj;
      }
    }
    #pragma unroll
    for (int i = 0; i < 2; ++i){
      const int qg = q0 + ty2 + i;
      #pragma unroll
      for (int j = 0; j < 4; ++j){
        const int kk2 = kt64 + tx + 16*j;
        float p = 0.f;
        if (kk2 <= qg) p = __expf(acc[i][j] * SCALE_QK + mk[kk2] - mi[i]) * rl[i];
        Ps[ty2 + i][tx + 16*j] = p;
      }
    }
    __syncthreads();
    #pragma unroll
    for (int it = 0; it < 8; ++it){
      int idx = tid + it * 256;
      int row = idx >> 5, fq = (idx & 31) * 4;
      float4 t4 = *(const float4*)(vbase + (size_t)(kt64 + row) * DH + fq);
      KVs[row][fq+0] = t4.x; KVs[row][fq+1] = t4.y; KVs[row][fq+2] = t4.z; KVs[row][fq+3] = t4.w;
    }
    if (tid < 64){
      float cs = 0.f;
      #pragma unroll
      for (int r = 0; r < 32; ++r) cs += Ps[r][tid];
      atomicAdd(colsum_all + h_ * SS + kt64 + tid, cs);
      if (recent) atomicAdd(colsum_recent + h_ * SS + kt64 + tid, cs);
    }
    __syncthreads();
    #pragma unroll 2
    for (int kk = 0; kk < 64; ++kk){
      float p0 = Ps[ty2][kk], p1 = Ps[ty2 + 1][kk];
      #pragma unroll
      for (int j = 0; j < 8; ++j){
        float vv = KVs[kk][tx + 16*j];
        o[0][j] += p0 * vv;
        o[1][j] += p1 * vv;
      }
    }
  }
  #pragma unroll
  for (int i = 0; i < 2; ++i){
    float* orow = attn_out + (size_t)(b_*SS + q0 + ty2 + i) * HIDN + h_ * DH;
    #pragma unroll
    for (int j = 0; j < 8; ++j) orow[tx + 16*j] = o[i][j];
  }
}

// ---------------- attention column at k = sb (from stored m,l) ----------------------------
__global__ __launch_bounds__(256) void k_colsb(
    const float* __restrict__ qg_, const float* __restrict__ kg_,
    const float* __restrict__ amask,
    const float* __restrict__ mrow, const float* __restrict__ lrow,
    float* __restrict__ acol)
{
  __shared__ __align__(16) float ksb[DH];
  const int tid = threadIdx.x;
  const int qc = blockIdx.x & 31;
  const int bh = blockIdx.x >> 5;
  const int b_ = bh >> 4;
  if (tid < 32)
    ((float4*)ksb)[tid] = ((const float4*)(kg_ + (size_t)(bh * SS + SBI) * DH))[tid];
  __syncthreads();
  const int ql = tid >> 2, part = tid & 3;
  const int qg = qc * 64 + ql;
  const float* qrow = qg_ + (size_t)(bh * SS + qg) * DH + part * 32;
  float acc = 0.f;
  #pragma unroll
  for (int t = 0; t < 8; ++t){
    float4 a4 = ((const float4*)qrow)[t];
    float4 k4 = ((const float4*)(ksb + part * 32))[t];
    acc += a4.x*k4.x + a4.y*k4.y + a4.z*k4.z + a4.w*k4.w;
  }
  acc += __shfl_xor(acc, 1);
  acc += __shfl_xor(acc, 2);
  if (part == 0){
    float a = 0.f;
    if (qg >= SBI){
      float m = mrow[(size_t)bh * SS + qg];
      float l = lrow[(size_t)bh * SS + qg];
      a = __expf(acc * SCALE_QK + amask[b_*SS + SBI] - m) / l;
    }
    acol[(size_t)bh * SS + qg] = a;
  }
}

// ---------------- topk per head + score1 ---------------------------------------------------
__global__ __launch_bounds__(256) void k_topk(
    const float* __restrict__ colsum_all, const float* __restrict__ colsum_recent,
    const float* __restrict__ vg_, float* __restrict__ score1)
{
  __shared__ float vals[KEEPEND];
  __shared__ float rv[256];
  __shared__ int   ri[256];
  __shared__ int   sidx[NTOPK];
  __shared__ float sratio[NTOPK];
  const int h_ = blockIdx.x;
  const int tid = threadIdx.x;
  for (int i = SBI + tid; i < KEEPEND; i += 256) vals[i] = colsum_all[h_*SS + i];
  __syncthreads();
  for (int it = 0; it < NTOPK; ++it){
    float bv = -1.f; int bi = 0x7fffffff;
    for (int i = SBI + tid; i < KEEPEND; i += 256){
      float x = vals[i];
      if (x > bv){ bv = x; bi = i; }
    }
    rv[tid] = bv; ri[tid] = bi;
    __syncthreads();
    for (int s2 = 128; s2 > 0; s2 >>= 1){
      if (tid < s2){
        float ov = rv[tid + s2]; int oi = ri[tid + s2];
        if (ov > rv[tid] || (ov == rv[tid] && oi < ri[tid])){ rv[tid] = ov; ri[tid] = oi; }
      }
      __syncthreads();
    }
    if (tid == 0){ sidx[it] = ri[0]; vals[ri[0]] = -1.f; }
    __syncthreads();
  }
  if (tid < NTOPK) sratio[tid] = colsum_recent[h_*SS + sidx[tid]] * (1.f / NREC);
  __syncthreads();
  const int b_ = tid >> 7, d = tid & 127;
  float acc = 0.f;
  #pragma unroll
  for (int j = 0; j < NTOPK; ++j)
    acc += sratio[j] * vg_[(size_t)((b_*NHH + h_)*SS + sidx[j])*DH + d];
  score1[(b_*NHH + h_)*DH + d] = acc;
}

// ---------------- rank-1 correction: out += attn[:,sb] * (score1 - v[sb]) ----------------
__global__ void k_corr(const float* __restrict__ acol, const float* __restrict__ score1,
                       const float* __restrict__ vg_, float* __restrict__ attn_out)
{
  const int idx = blockIdx.x * 256 + threadIdx.x;
  const int dq = idx & 31;
  int t = idx >> 5;
  const int qg = t & (SS - 1); t >>= 11;
  const int h_ = t & 15;
  const int b_ = t >> 4;
  const float a = acol[(size_t)(b_*NHH + h_) * SS + qg];
  if (a != 0.f){
    const int d = dq * 4;
    const float4 s1 = *(const float4*)(score1 + (b_*NHH + h_) * DH + d);
    const float4 vs = *(const float4*)(vg_ + (size_t)((b_*NHH + h_)*SS + SBI) * DH + d);
    float4* op = (float4*)(attn_out + (size_t)(b_*SS + qg) * HIDN + h_ * DH + d);
    float4 ov = *op;
    ov.x += a * (s1.x - vs.x);
    ov.y += a * (s1.y - vs.y);
    ov.z += a * (s1.z - vs.z);
    ov.w += a * (s1.w - vs.w);
    *op = ov;
  }
}

extern "C" void kernel_launch(void* const* d_in, const int* in_sizes, int n_in,
                              void* d_out, int out_size, void* d_ws, size_t ws_size,
                              hipStream_t stream)
{
  (void)in_sizes; (void)n_in; (void)out_size; (void)ws_size;
  const float* hs    = (const float*)d_in[0];
  const float* amask = (const float*)d_in[1];
  const int*   pos   = (const int*)d_in[2];
  const float* Wqkv  = (const float*)d_in[3];
  const float* bqkv  = (const float*)d_in[4];
  const float* Wd    = (const float*)d_in[5];
  const float* bd    = (const float*)d_in[6];
  float* out = (float*)d_out;
  float* ws  = (float*)d_ws;

  const size_t SZ = (size_t)NB * NHH * SS * DH;       // 8,388,608
  float* q             = ws;
  float* k             = q + SZ;
  float* v             = k + SZ;
  float* attn_out      = v + SZ;                       // B*S*HID
  float* mrow          = attn_out + SZ;                // B*H*S
  float* lrow          = mrow + (size_t)NB*NHH*SS;
  float* colsum_all    = lrow + (size_t)NB*NHH*SS;     // H*S
  float* colsum_recent = colsum_all + (size_t)NHH*SS;  // H*S
  float* acol          = colsum_recent + (size_t)NHH*SS;
  float* score1        = acol + (size_t)NB*NHH*SS;     // B*H*D
  float* bfstart       = score1 + (size_t)NB*NHH*DH;
  unsigned short* hs_bf = (unsigned short*)bfstart;             // 8.4M ushort
  unsigned short* ao_bf = hs_bf;                                // alias: hs_bf dead after qkv GEMM
  unsigned short* Wq_bf = hs_bf + SZ;                           // 12.6M ushort
  unsigned short* Wd_bf = Wq_bf + (size_t)3*HIDN*HIDN;          // 4.2M ushort

  k_zero<<<256, 256, 0, stream>>>(colsum_all, NHH * SS * 2);
  k_f2bf<<<4096, 256, 0, stream>>>(hs,   hs_bf, (int)(SZ / 8));
  k_f2bf<<<6144, 256, 0, stream>>>(Wqkv, Wq_bf, (int)(3*HIDN*HIDN / 8));
  k_f2bf<<<2048, 256, 0, stream>>>(Wd,   Wd_bf, (int)(HIDN*HIDN / 8));

  k_gemm_qkv<<<dim3(48, 32), 256, 0, stream>>>(hs_bf, Wq_bf, bqkv, pos, q, k, v);

  k_passA<<<NB*NHH*(SS/32), 256, 0, stream>>>(q, k, amask, mrow, lrow);
  k_passB<<<NB*NHH*(SS/32), 256, 0, stream>>>(q, k, v, amask, mrow, lrow,
                                              attn_out, colsum_all, colsum_recent);
  k_colsb<<<NB*NHH*(SS/64), 256, 0, stream>>>(q, k, amask, mrow, lrow, acol);
  k_topk<<<NHH, 256, 0, stream>>>(colsum_all, colsum_recent, v, score1);
  k_corr<<<(NB*NHH*SS*32)/256, 256, 0, stream>>>(acol, score1, v, attn_out);

  k_f2bf<<<4096, 256, 0, stream>>>(attn_out, ao_bf, (int)(SZ / 8));
  k_gemm_dense<<<dim3(16, 32), 256, 0, stream>>>(ao_bf, Wd_bf, bd, out);
}

// Round 3
// 635.923 us; speedup vs baseline: 7.5190x; 4.0681x over previous
//
#include <hip/hip_runtime.h>
#include <cfloat>
#include <math.h>

// Problem constants
#define NB 2
#define SS 2048
#define HIDN 2048
#define NHH 16
#define DH 128
#define SBI 204       // int(0.1*S)
#define KEEPEND 1844  // S - int(0.1*S)
#define NREC 128      // MERGE_BUDGET
#define NTOPK 16

typedef short bf16x8 __attribute__((ext_vector_type(8)));
typedef short bf16x4 __attribute__((ext_vector_type(4)));
typedef float f32x4  __attribute__((ext_vector_type(4)));
typedef unsigned short ushort8_v __attribute__((ext_vector_type(8)));

#define GLOBAL_AS __attribute__((address_space(1)))
#define LDS_AS    __attribute__((address_space(3)))

__device__ __forceinline__ void async16(const unsigned short* g, unsigned short* l){
  __builtin_amdgcn_global_load_lds((const GLOBAL_AS void*)g, (LDS_AS void*)l, 16, 0, 0);
}

__device__ __forceinline__ unsigned short f2bf(float x){
  union { float f; unsigned u; } cv; cv.f = x;
  unsigned u = cv.u;
  return (unsigned short)((u + 0x7fffu + ((u >> 16) & 1u)) >> 16);
}
__device__ __forceinline__ float bf2f(unsigned short u){
  union { unsigned u; float f; } cv; cv.u = ((unsigned)u) << 16;
  return cv.f;
}

__device__ __forceinline__ float wave16_max(float x){
  x = fmaxf(x, __shfl_xor(x, 1));
  x = fmaxf(x, __shfl_xor(x, 2));
  x = fmaxf(x, __shfl_xor(x, 4));
  x = fmaxf(x, __shfl_xor(x, 8));
  return x;
}
__device__ __forceinline__ float wave16_sum(float x){
  x += __shfl_xor(x, 1);
  x += __shfl_xor(x, 2);
  x += __shfl_xor(x, 4);
  x += __shfl_xor(x, 8);
  return x;
}

__constant__ const float SCALE_QK = 0.08838834764831845f; // 1/sqrt(128)

__global__ void k_zero(float* __restrict__ p, int n){
  int i = blockIdx.x * 256 + threadIdx.x;
  if (i < n) p[i] = 0.f;
}

// ---------------- fp32 -> bf16 convert (8 elems/thread) -----------------------------------
__global__ void k_f2bf(const float* __restrict__ src, unsigned short* __restrict__ dst, int n8){
  int i = blockIdx.x * 256 + threadIdx.x;
  if (i >= n8) return;
  const float4* s = (const float4*)src + (size_t)i * 2;
  float4 a = s[0], b = s[1];
  ushort8_v r;
  r[0] = f2bf(a.x); r[1] = f2bf(a.y); r[2] = f2bf(a.z); r[3] = f2bf(a.w);
  r[4] = f2bf(b.x); r[5] = f2bf(b.y); r[6] = f2bf(b.z); r[7] = f2bf(b.w);
  *(ushort8_v*)(dst + (size_t)i * 8) = r;
}

// ---------------- bf16 MFMA GEMM: QKV variant, writes bf16 q/k/v with fused RoPE ----------
__global__ __launch_bounds__(256) void k_gemm_qkv(
    const unsigned short* __restrict__ A, const unsigned short* __restrict__ W,
    const float* __restrict__ bias, const int* __restrict__ pos,
    unsigned short* __restrict__ q, unsigned short* __restrict__ k,
    unsigned short* __restrict__ v)
{
  __shared__ __align__(16) unsigned short As[128 * 32];
  __shared__ __align__(16) unsigned short Bs[128 * 32];
  const int tid  = threadIdx.x;
  const int lane = tid & 63, w = tid >> 6;
  const int wm = w >> 1, wn = w & 1;
  const int quad = lane >> 4, m16 = lane & 15;
  const int cb   = blockIdx.x;
  const int row0 = blockIdx.y * 128;
  const int col0 = cb * 128;

  const int srow = tid >> 2;
  const int scol = (tid & 3) * 8;
  const unsigned short* ga = A + (size_t)(row0 + srow) * HIDN + scol;
  const unsigned short* gb = W + (size_t)(col0 + srow) * HIDN + scol;
  unsigned short* la = As + tid * 8;
  unsigned short* lb = Bs + tid * 8;

  f32x4 acc[4][4];
  #pragma unroll
  for (int i = 0; i < 4; ++i)
    #pragma unroll
    for (int j = 0; j < 4; ++j)
      acc[i][j] = (f32x4){0.f, 0.f, 0.f, 0.f};

  for (int k0 = 0; k0 < HIDN; k0 += 32){
    __syncthreads();
    async16(ga + k0,             la);
    async16(ga + k0 + 64 * HIDN, la + 64 * 32);
    async16(gb + k0,             lb);
    async16(gb + k0 + 64 * HIDN, lb + 64 * 32);
    __syncthreads();
    bf16x8 af[4], bf[4];
    #pragma unroll
    for (int j = 0; j < 4; ++j)
      bf[j] = *(const bf16x8*)(Bs + (wn * 64 + j * 16 + m16) * 32 + quad * 8);
    #pragma unroll
    for (int i = 0; i < 4; ++i)
      af[i] = *(const bf16x8*)(As + (wm * 64 + i * 16 + m16) * 32 + quad * 8);
    #pragma unroll
    for (int i = 0; i < 4; ++i)
      #pragma unroll
      for (int j = 0; j < 4; ++j)
        acc[i][j] = __builtin_amdgcn_mfma_f32_16x16x32_bf16(af[i], bf[j], acc[i][j], 0, 0, 0);
  }

  const int h  = cb / 3, r3 = cb - 3 * (cb / 3);
  unsigned short* dst = (r3 == 0) ? q : ((r3 == 1) ? k : v);
  const bool do_rope = (r3 < 2) && (wn == 0);
  const float invf = __expf(-(float)m16 * 0.5756462732485115f); // ln(10000)/16

  #pragma unroll
  for (int i = 0; i < 4; ++i){
    #pragma unroll
    for (int reg = 0; reg < 4; ++reg){
      const int mr = row0 + wm * 64 + i * 16 + quad * 4 + reg;
      const int b_ = mr >> 11, s_ = mr & (SS - 1);
      unsigned short* drow = dst + (size_t)((b_ * NHH + h) * SS + s_) * DH;
      float vals[4];
      #pragma unroll
      for (int j = 0; j < 4; ++j)
        vals[j] = acc[i][j][reg] + bias[col0 + wn * 64 + j * 16 + m16];
      if (do_rope){
        float sn, cs;
        const float p = (float)pos[b_ * SS + s_];
        sincosf(p * invf, &sn, &cs);
        const float x0 = vals[0], x1 = vals[1];
        vals[0] = x0 * cs - x1 * sn;
        vals[1] = x1 * cs + x0 * sn;
      }
      #pragma unroll
      for (int j = 0; j < 4; ++j)
        drow[wn * 64 + j * 16 + m16] = f2bf(vals[j]);
    }
  }
}

// Dense variant: plain C = A @ W^T + bias (fp32 out)
__global__ __launch_bounds__(256) void k_gemm_dense(
    const unsigned short* __restrict__ A, const unsigned short* __restrict__ W,
    const float* __restrict__ bias, float* __restrict__ out)
{
  __shared__ __align__(16) unsigned short As[128 * 32];
  __shared__ __align__(16) unsigned short Bs[128 * 32];
  const int tid  = threadIdx.x;
  const int lane = tid & 63, w = tid >> 6;
  const int wm = w >> 1, wn = w & 1;
  const int quad = lane >> 4, m16 = lane & 15;
  const int row0 = blockIdx.y * 128;
  const int col0 = blockIdx.x * 128;

  const int srow = tid >> 2;
  const int scol = (tid & 3) * 8;
  const unsigned short* ga = A + (size_t)(row0 + srow) * HIDN + scol;
  const unsigned short* gb = W + (size_t)(col0 + srow) * HIDN + scol;
  unsigned short* la = As + tid * 8;
  unsigned short* lb = Bs + tid * 8;

  f32x4 acc[4][4];
  #pragma unroll
  for (int i = 0; i < 4; ++i)
    #pragma unroll
    for (int j = 0; j < 4; ++j)
      acc[i][j] = (f32x4){0.f, 0.f, 0.f, 0.f};

  for (int k0 = 0; k0 < HIDN; k0 += 32){
    __syncthreads();
    async16(ga + k0,             la);
    async16(ga + k0 + 64 * HIDN, la + 64 * 32);
    async16(gb + k0,             lb);
    async16(gb + k0 + 64 * HIDN, lb + 64 * 32);
    __syncthreads();
    bf16x8 af[4], bf[4];
    #pragma unroll
    for (int j = 0; j < 4; ++j)
      bf[j] = *(const bf16x8*)(Bs + (wn * 64 + j * 16 + m16) * 32 + quad * 8);
    #pragma unroll
    for (int i = 0; i < 4; ++i)
      af[i] = *(const bf16x8*)(As + (wm * 64 + i * 16 + m16) * 32 + quad * 8);
    #pragma unroll
    for (int i = 0; i < 4; ++i)
      #pragma unroll
      for (int j = 0; j < 4; ++j)
        acc[i][j] = __builtin_amdgcn_mfma_f32_16x16x32_bf16(af[i], bf[j], acc[i][j], 0, 0, 0);
  }

  #pragma unroll
  for (int i = 0; i < 4; ++i){
    #pragma unroll
    for (int reg = 0; reg < 4; ++reg){
      const int mr = row0 + wm * 64 + i * 16 + quad * 4 + reg;
      #pragma unroll
      for (int j = 0; j < 4; ++j){
        const int c = col0 + wn * 64 + j * 16 + m16;
        out[(size_t)mr * HIDN + c] = acc[i][j][reg] + bias[c];
      }
    }
  }
}

// ---------------- V transpose with k-permutation: Vt[bh][d][perm(s)] ----------------------
// perm within each 64-chunk: slot(k) = (k&15)*4 + (k>>4), k = s & 63.
__global__ __launch_bounds__(256) void k_vt(
    const unsigned short* __restrict__ v, unsigned short* __restrict__ vt)
{
  __shared__ unsigned short ld[64 * 136];
  const int tid = threadIdx.x;
  const int st = blockIdx.x;        // s-tile (64 rows)
  const int bh = blockIdx.y;
  const int s0 = st * 64;
  #pragma unroll
  for (int it = 0; it < 4; ++it){
    int vv = tid + it * 256;
    int row = vv >> 4, cv = (vv & 15) * 8;
    *(bf16x8*)(ld + row * 136 + cv) =
        *(const bf16x8*)(v + (size_t)(bh * SS + s0 + row) * DH + cv);
  }
  __syncthreads();
  const int d = tid >> 1, h2 = tid & 1;
  unsigned short* orow = vt + (size_t)(bh * DH + d) * SS + s0 + h2 * 32;
  #pragma unroll
  for (int g = 0; g < 4; ++g){
    ushort8_v pk;
    #pragma unroll
    for (int e = 0; e < 8; ++e){
      const int slot = h2 * 32 + g * 8 + e;
      const int kl = (slot & 3) * 16 + (slot >> 2);   // inverse perm
      pk[e] = ld[kl * 136 + d];
    }
    *(ushort8_v*)(orow + g * 8) = pk;
  }
}

// ---------------- Fused two-pass MFMA flash attention -------------------------------------
// grid (S/128, B*H), 256 threads = 4 waves; wave w owns q rows [w*32, w*32+32).
__global__ __launch_bounds__(256, 2) void k_fattn(
    const unsigned short* __restrict__ qg, const unsigned short* __restrict__ kg,
    const unsigned short* __restrict__ vtg, const float* __restrict__ amask,
    float* __restrict__ mrow, float* __restrict__ lrow,
    float* __restrict__ attn_out,
    float* __restrict__ colsum_all, float* __restrict__ colsum_recent)
{
  __shared__ __align__(16) unsigned short Ks[64 * 136];
  __shared__ __align__(16) unsigned short Ps[128 * 72];
  __shared__ __align__(16) unsigned short Vt[128 * 72];
  __shared__ float colbuf[64];

  const int tid  = threadIdx.x;
  const int lane = tid & 63, w = tid >> 6;
  const int quad = lane >> 4, m16 = lane & 15;
  const int qt = blockIdx.x, bh = blockIdx.y;
  const int b_ = bh >> 4, h_ = bh & 15;
  const int q0 = qt * 128;
  const int rbase = w * 32;
  const unsigned short* qb  = qg  + (size_t)bh * SS * DH;
  const unsigned short* kb  = kg  + (size_t)bh * SS * DH;
  const unsigned short* vtb = vtg + (size_t)bh * DH * SS;
  const float* mk = amask + b_ * SS;
  const int nkt = 2 * qt + 2;

  // Q fragments in registers
  bf16x8 Qf[2][4];
  #pragma unroll
  for (int i = 0; i < 2; ++i)
    #pragma unroll
    for (int ds = 0; ds < 4; ++ds)
      Qf[i][ds] = *(const bf16x8*)(qb + (size_t)(q0 + rbase + i * 16 + m16) * DH + ds * 32 + quad * 8);

  // ---------------- pass A: m, l ----------------
  float m_run[2][4], l_run[2][4];
  #pragma unroll
  for (int i = 0; i < 2; ++i)
    #pragma unroll
    for (int r = 0; r < 4; ++r){ m_run[i][r] = -FLT_MAX; l_run[i][r] = 0.f; }

  for (int kt = 0; kt < nkt; ++kt){
    const int kt64 = kt * 64;
    __syncthreads();
    #pragma unroll
    for (int it = 0; it < 4; ++it){
      int vv = tid + it * 256;
      int row = vv >> 4, cv = (vv & 15) * 8;
      *(bf16x8*)(Ks + row * 136 + cv) =
          *(const bf16x8*)(kb + (size_t)(kt64 + row) * DH + cv);
    }
    __syncthreads();
    f32x4 acc[2][4];
    #pragma unroll
    for (int i = 0; i < 2; ++i)
      #pragma unroll
      for (int j = 0; j < 4; ++j) acc[i][j] = (f32x4){0.f,0.f,0.f,0.f};
    #pragma unroll
    for (int ds = 0; ds < 4; ++ds){
      bf16x8 Bf[4];
      #pragma unroll
      for (int j = 0; j < 4; ++j)
        Bf[j] = *(const bf16x8*)(Ks + (j * 16 + m16) * 136 + ds * 32 + quad * 8);
      #pragma unroll
      for (int i = 0; i < 2; ++i)
        #pragma unroll
        for (int j = 0; j < 4; ++j)
          acc[i][j] = __builtin_amdgcn_mfma_f32_16x16x32_bf16(Qf[i][ds], Bf[j], acc[i][j], 0, 0, 0);
    }
    float mkv[4];
    #pragma unroll
    for (int j = 0; j < 4; ++j) mkv[j] = mk[kt64 + j * 16 + m16];
    const bool full = (kt64 + 63 <= q0);
    #pragma unroll
    for (int i = 0; i < 2; ++i){
      #pragma unroll
      for (int r = 0; r < 4; ++r){
        const int qrow = q0 + rbase + i * 16 + quad * 4 + r;
        float s[4], tmax = -FLT_MAX;
        #pragma unroll
        for (int j = 0; j < 4; ++j){
          const int kc = kt64 + j * 16 + m16;
          float sv = acc[i][j][r] * SCALE_QK + mkv[j];
          if (!full && kc > qrow) sv = -FLT_MAX;
          s[j] = sv;
          tmax = fmaxf(tmax, sv);
        }
        tmax = wave16_max(tmax);
        if (tmax > -1e37f){
          float ts = 0.f;
          #pragma unroll
          for (int j = 0; j < 4; ++j) ts += __expf(s[j] - tmax);
          ts = wave16_sum(ts);
          const float mn = fmaxf(m_run[i][r], tmax);
          l_run[i][r] = l_run[i][r] * __expf(m_run[i][r] - mn) + ts * __expf(tmax - mn);
          m_run[i][r] = mn;
        }
      }
    }
  }

  // export m,l ; build reciprocals
  float rl[2][4];
  #pragma unroll
  for (int i = 0; i < 2; ++i)
    #pragma unroll
    for (int r = 0; r < 4; ++r){
      rl[i][r] = 1.f / l_run[i][r];
      if (m16 == 0){
        const int qrow = q0 + rbase + i * 16 + quad * 4 + r;
        mrow[(size_t)bh * SS + qrow] = m_run[i][r];
        lrow[(size_t)bh * SS + qrow] = l_run[i][r];
      }
    }

  // ---------------- pass B: exact P, colsums, PV ----------------
  f32x4 o[2][8];
  #pragma unroll
  for (int i = 0; i < 2; ++i)
    #pragma unroll
    for (int jd = 0; jd < 8; ++jd) o[i][jd] = (f32x4){0.f,0.f,0.f,0.f};

  for (int kt = 0; kt < nkt; ++kt){
    const int kt64 = kt * 64;
    __syncthreads();   // prev PV + colbuf flush done
    #pragma unroll
    for (int it = 0; it < 4; ++it){
      int vv = tid + it * 256;
      int row = vv >> 4, cv = (vv & 15) * 8;
      *(bf16x8*)(Ks + row * 136 + cv) =
          *(const bf16x8*)(kb + (size_t)(kt64 + row) * DH + cv);
    }
    #pragma unroll
    for (int it = 0; it < 4; ++it){
      int vv = tid + it * 256;
      int d = vv >> 3, cv = (vv & 7) * 8;
      *(bf16x8*)(Vt + d * 72 + cv) =
          *(const bf16x8*)(vtb + (size_t)d * SS + kt64 + cv);
    }
    if (tid < 64) colbuf[tid] = 0.f;
    __syncthreads();
    f32x4 acc[2][4];
    #pragma unroll
    for (int i = 0; i < 2; ++i)
      #pragma unroll
      for (int j = 0; j < 4; ++j) acc[i][j] = (f32x4){0.f,0.f,0.f,0.f};
    #pragma unroll
    for (int ds = 0; ds < 4; ++ds){
      bf16x8 Bf[4];
      #pragma unroll
      for (int j = 0; j < 4; ++j)
        Bf[j] = *(const bf16x8*)(Ks + (j * 16 + m16) * 136 + ds * 32 + quad * 8);
      #pragma unroll
      for (int i = 0; i < 2; ++i)
        #pragma unroll
        for (int j = 0; j < 4; ++j)
          acc[i][j] = __builtin_amdgcn_mfma_f32_16x16x32_bf16(Qf[i][ds], Bf[j], acc[i][j], 0, 0, 0);
    }
    float mkv[4];
    #pragma unroll
    for (int j = 0; j < 4; ++j) mkv[j] = mk[kt64 + j * 16 + m16];
    const bool full = (kt64 + 63 <= q0);
    float colpart[4] = {0.f, 0.f, 0.f, 0.f};
    #pragma unroll
    for (int i = 0; i < 2; ++i){
      #pragma unroll
      for (int r = 0; r < 4; ++r){
        const int qrow = q0 + rbase + i * 16 + quad * 4 + r;
        bf16x4 pk;
        #pragma unroll
        for (int j = 0; j < 4; ++j){
          const int kc = kt64 + j * 16 + m16;
          float pv = __expf(acc[i][j][r] * SCALE_QK + mkv[j] - m_run[i][r]) * rl[i][r];
          if (!full && kc > qrow) pv = 0.f;
          colpart[j] += pv;
          pk[j] = (short)f2bf(pv);
        }
        // row-major Ps[q][slot], slot = m16*4 + j (k-permuted; V^T uses same perm)
        *(bf16x4*)(Ps + (rbase + i * 16 + quad * 4 + r) * 72 + m16 * 4) = pk;
      }
    }
    #pragma unroll
    for (int j = 0; j < 4; ++j){
      float c = colpart[j];
      c += __shfl_xor(c, 16);
      c += __shfl_xor(c, 32);
      if (quad == 0) atomicAdd(&colbuf[j * 16 + m16], c);
    }
    __syncthreads();   // Ps, Vt, colbuf complete
    #pragma unroll
    for (int ks = 0; ks < 2; ++ks){
      bf16x8 Af[2];
      #pragma unroll
      for (int i = 0; i < 2; ++i)
        Af[i] = *(const bf16x8*)(Ps + (rbase + i * 16 + m16) * 72 + ks * 32 + quad * 8);
      #pragma unroll
      for (int jd = 0; jd < 8; ++jd){
        bf16x8 Bf = *(const bf16x8*)(Vt + (jd * 16 + m16) * 72 + ks * 32 + quad * 8);
        #pragma unroll
        for (int i = 0; i < 2; ++i)
          o[i][jd] = __builtin_amdgcn_mfma_f32_16x16x32_bf16(Af[i], Bf, o[i][jd], 0, 0, 0);
      }
    }
    if (tid < 64){
      const float c = colbuf[tid];
      atomicAdd(colsum_all + h_ * SS + kt64 + tid, c);
      if (q0 == SS - 128) atomicAdd(colsum_recent + h_ * SS + kt64 + tid, c);
    }
  }

  // epilogue: write O (fp32)
  #pragma unroll
  for (int i = 0; i < 2; ++i){
    #pragma unroll
    for (int r = 0; r < 4; ++r){
      const int qrow = q0 + rbase + i * 16 + quad * 4 + r;
      float* orow = attn_out + (size_t)(b_ * SS + qrow) * HIDN + h_ * DH;
      #pragma unroll
      for (int jd = 0; jd < 8; ++jd)
        orow[jd * 16 + m16] = o[i][jd][r];
    }
  }
}

// ---------------- attention column at k = sb (from stored m,l) ----------------------------
__global__ __launch_bounds__(256) void k_colsb(
    const unsigned short* __restrict__ qg, const unsigned short* __restrict__ kg,
    const float* __restrict__ amask,
    const float* __restrict__ mrow, const float* __restrict__ lrow,
    float* __restrict__ acol)
{
  __shared__ __align__(16) float ksb[DH];
  const int tid = threadIdx.x;
  const int qc = blockIdx.x & 31;
  const int bh = blockIdx.x >> 5;
  const int b_ = bh >> 4;
  if (tid < 16){
    ushort8_v t = ((const ushort8_v*)(kg + (size_t)(bh * SS + SBI) * DH))[tid];
    #pragma unroll
    for (int e = 0; e < 8; ++e) ksb[tid * 8 + e] = bf2f(t[e]);
  }
  __syncthreads();
  const int ql = tid >> 2, part = tid & 3;
  const int qrow = qc * 64 + ql;
  const unsigned short* qr = qg + (size_t)(bh * SS + qrow) * DH + part * 32;
  float acc = 0.f;
  #pragma unroll
  for (int t = 0; t < 4; ++t){
    ushort8_v a = ((const ushort8_v*)qr)[t];
    #pragma unroll
    for (int e = 0; e < 8; ++e)
      acc += bf2f(a[e]) * ksb[part * 32 + t * 8 + e];
  }
  acc += __shfl_xor(acc, 1);
  acc += __shfl_xor(acc, 2);
  if (part == 0){
    float a = 0.f;
    if (qrow >= SBI){
      const float m = mrow[(size_t)bh * SS + qrow];
      const float l = lrow[(size_t)bh * SS + qrow];
      a = __expf(acc * SCALE_QK + amask[b_ * SS + SBI] - m) / l;
    }
    acol[(size_t)bh * SS + qrow] = a;
  }
}

// ---------------- topk per head + score1 ---------------------------------------------------
__global__ __launch_bounds__(256) void k_topk(
    const float* __restrict__ colsum_all, const float* __restrict__ colsum_recent,
    const unsigned short* __restrict__ vg_, float* __restrict__ score1)
{
  __shared__ float vals[KEEPEND];
  __shared__ float rv[256];
  __shared__ int   ri[256];
  __shared__ int   sidx[NTOPK];
  __shared__ float sratio[NTOPK];
  const int h_ = blockIdx.x;
  const int tid = threadIdx.x;
  for (int i = SBI + tid; i < KEEPEND; i += 256) vals[i] = colsum_all[h_*SS + i];
  __syncthreads();
  for (int it = 0; it < NTOPK; ++it){
    float bv = -1.f; int bi = 0x7fffffff;
    for (int i = SBI + tid; i < KEEPEND; i += 256){
      float x = vals[i];
      if (x > bv){ bv = x; bi = i; }
    }
    rv[tid] = bv; ri[tid] = bi;
    __syncthreads();
    for (int s2 = 128; s2 > 0; s2 >>= 1){
      if (tid < s2){
        float ov = rv[tid + s2]; int oi = ri[tid + s2];
        if (ov > rv[tid] || (ov == rv[tid] && oi < ri[tid])){ rv[tid] = ov; ri[tid] = oi; }
      }
      __syncthreads();
    }
    if (tid == 0){ sidx[it] = ri[0]; vals[ri[0]] = -1.f; }
    __syncthreads();
  }
  if (tid < NTOPK) sratio[tid] = colsum_recent[h_*SS + sidx[tid]] * (1.f / NREC);
  __syncthreads();
  const int b_ = tid >> 7, d = tid & 127;
  float acc = 0.f;
  #pragma unroll
  for (int j = 0; j < NTOPK; ++j)
    acc += sratio[j] * bf2f(vg_[(size_t)((b_*NHH + h_)*SS + sidx[j])*DH + d]);
  score1[(b_*NHH + h_)*DH + d] = acc;
}

// ---------------- rank-1 correction: out += attn[:,sb] * (score1 - v[sb]) ----------------
__global__ void k_corr(const float* __restrict__ acol, const float* __restrict__ score1,
                       const unsigned short* __restrict__ vg_, float* __restrict__ attn_out)
{
  const int idx = blockIdx.x * 256 + threadIdx.x;
  const int dq = idx & 31;
  int t = idx >> 5;
  const int qg = t & (SS - 1); t >>= 11;
  const int h_ = t & 15;
  const int b_ = t >> 4;
  const float a = acol[(size_t)(b_*NHH + h_) * SS + qg];
  if (a != 0.f){
    const int d = dq * 4;
    const float4 s1 = *(const float4*)(score1 + (b_*NHH + h_) * DH + d);
    const unsigned short* vsp = vg_ + (size_t)((b_*NHH + h_)*SS + SBI) * DH + d;
    float4* op = (float4*)(attn_out + (size_t)(b_*SS + qg) * HIDN + h_ * DH + d);
    float4 ov = *op;
    ov.x += a * (s1.x - bf2f(vsp[0]));
    ov.y += a * (s1.y - bf2f(vsp[1]));
    ov.z += a * (s1.z - bf2f(vsp[2]));
    ov.w += a * (s1.w - bf2f(vsp[3]));
    *op = ov;
  }
}

extern "C" void kernel_launch(void* const* d_in, const int* in_sizes, int n_in,
                              void* d_out, int out_size, void* d_ws, size_t ws_size,
                              hipStream_t stream)
{
  (void)in_sizes; (void)n_in; (void)out_size; (void)ws_size;
  const float* hs    = (const float*)d_in[0];
  const float* amask = (const float*)d_in[1];
  const int*   pos   = (const int*)d_in[2];
  const float* Wqkv  = (const float*)d_in[3];
  const float* bqkv  = (const float*)d_in[4];
  const float* Wd    = (const float*)d_in[5];
  const float* bd    = (const float*)d_in[6];
  float* out = (float*)d_out;

  const size_t SZ   = (size_t)NB * NHH * SS * DH;   // 8,388,608
  const size_t NBHS = (size_t)NB * NHH * SS;        // 65,536
  const size_t HS   = (size_t)NHH * SS;             // 32,768

  float* attn_out      = (float*)d_ws;
  float* mrow          = attn_out + SZ;
  float* lrow          = mrow + NBHS;
  float* colsum_all    = lrow + NBHS;
  float* colsum_recent = colsum_all + HS;
  float* acol          = colsum_recent + HS;
  float* score1        = acol + NBHS;
  unsigned short* q_bf  = (unsigned short*)(score1 + (size_t)NB*NHH*DH);
  unsigned short* k_bf  = q_bf + SZ;
  unsigned short* v_bf  = k_bf + SZ;
  unsigned short* vt_bf = v_bf + SZ;
  unsigned short* hs_bf = vt_bf + SZ;               // also reused as ao_bf
  unsigned short* Wq_bf = hs_bf + SZ;
  unsigned short* Wd_bf = Wq_bf + (size_t)3*HIDN*HIDN;

  k_zero<<<256, 256, 0, stream>>>(colsum_all, (int)(2 * HS));
  k_f2bf<<<4096, 256, 0, stream>>>(hs,   hs_bf, (int)(SZ / 8));
  k_f2bf<<<6144, 256, 0, stream>>>(Wqkv, Wq_bf, (int)(3*HIDN*HIDN / 8));
  k_f2bf<<<2048, 256, 0, stream>>>(Wd,   Wd_bf, (int)(HIDN*HIDN / 8));

  k_gemm_qkv<<<dim3(48, 32), 256, 0, stream>>>(hs_bf, Wq_bf, bqkv, pos, q_bf, k_bf, v_bf);
  k_vt<<<dim3(32, 32), 256, 0, stream>>>(v_bf, vt_bf);

  k_fattn<<<dim3(16, 32), 256, 0, stream>>>(q_bf, k_bf, vt_bf, amask, mrow, lrow,
                                            attn_out, colsum_all, colsum_recent);

  k_colsb<<<NB*NHH*(SS/64), 256, 0, stream>>>(q_bf, k_bf, amask, mrow, lrow, acol);
  k_topk<<<NHH, 256, 0, stream>>>(colsum_all, colsum_recent, v_bf, score1);
  k_corr<<<(NB*NHH*SS*32)/256, 256, 0, stream>>>(acol, score1, v_bf, attn_out);

  k_f2bf<<<4096, 256, 0, stream>>>(attn_out, hs_bf, (int)(SZ / 8));
  k_gemm_dense<<<dim3(16, 32), 256, 0, stream>>>(hs_bf, Wd_bf, bd, out);
}